// Round 7
// baseline (577.260 us; speedup 1.0000x reference)
//
#include <hip/hip_runtime.h>
#include <hip/hip_bf16.h>
#include <math.h>
#include <stdint.h>

#define N_NODES 100000
#define N_EDGES 3200000
#define D 64
#define NUM_RELS 20
#define HID_ATTR 32
#define OUT_ATTR 10
#define PADR 72                          // A-tile row stride in bf16 (144 B)
#define NFB (N_NODES / 16)               // 6250 fused blocks (16 nodes each)

// two-level MSD counting sort
#define BUCKET_DSTS 256                  // dsts per coarse bucket (dst >> 8)
#define NB 391                           // ceil(100000 / 256)
#define PA_THREADS 512
#define PA_EPT 16                        // edges per thread
#define PA_CHUNK (PA_THREADS * PA_EPT)   // 8192
#define PA_GRID 391                      // ceil(3.2M / 8192)
#define PB_BINS (BUCKET_DSTS * NUM_RELS) // 5120 fine bins per bucket

typedef __attribute__((ext_vector_type(8))) short bf16x8;
typedef __attribute__((ext_vector_type(4))) float f32x4;

static __device__ __forceinline__ unsigned short f2bf(float x) {
    unsigned u = __builtin_bit_cast(unsigned, x);
    unsigned r = (u + 0x7FFFu + ((u >> 16) & 1u)) >> 16;
    return (unsigned short)r;
}
static __device__ __forceinline__ float bf2f(unsigned short b) {
    return __builtin_bit_cast(float, (unsigned)b << 16);
}
static __device__ __forceinline__ float bf2f_lo(unsigned u) {
    return __builtin_bit_cast(float, u << 16);
}
static __device__ __forceinline__ float bf2f_hi(unsigned u) {
    return __builtin_bit_cast(float, u & 0xFFFF0000u);
}
// packed f32->bf16 RNE (bit-identical to f2bf above for finite inputs)
static __device__ __forceinline__ unsigned cvt_pk_bf16(float lo, float hi) {
    unsigned r;
    asm("v_cvt_pk_bf16_f32 %0, %1, %2" : "=v"(r) : "v"(lo), "v"(hi));
    return r;
}

// ---------------- CSR build: 2-level MSD counting sort + balanced schedule --
// level 1 key: dst >> 8 (391 buckets); level 2 key: (dst&255)*20 + rel.
// tmp payload u32: dstLow[29:22] | src[21:5] | rel[4:0]
// passB: per 16-node fused-block, split each node into 4 rel-quarter walks
// (64 walks), bitonic-sort lengths desc, fold-pair rank k with rank 63-k onto
// 32 group slots, lay edges out in schedule order, emit sched_off[fb*32+g].
// Final edgedata payload: src[16:0] | rowoff[31:17],
//   rowoff = rel*(16*PADR) + (dstLow&15)*PADR  (<= 22968 < 2^15).
// Runs (same (dst,rel)) stay contiguous & whole.

__global__ void hist_bucket_kernel(const int* __restrict__ dst, int* __restrict__ hist) {
    __shared__ int h[NB];
    for (int i = threadIdx.x; i < NB; i += PA_THREADS) h[i] = 0;
    __syncthreads();
    int base = blockIdx.x * PA_CHUNK;
#pragma unroll
    for (int k = 0; k < PA_EPT; ++k) {
        int e = base + k * PA_THREADS + threadIdx.x;
        if (e < N_EDGES) atomicAdd(&h[dst[e] >> 8], 1);
    }
    __syncthreads();
    for (int i = threadIdx.x; i < NB; i += PA_THREADS)
        if (h[i]) atomicAdd(&hist[i], h[i]);
}

__global__ void scan_bucket_kernel(const int* __restrict__ hist, int* __restrict__ bbase,
                                   int* __restrict__ bcur, int* __restrict__ sched_off) {
    __shared__ int s[512];
    int t = threadIdx.x;
    int v = (t < NB) ? hist[t] : 0;
    s[t] = v;
    __syncthreads();
    for (int d2 = 1; d2 < 512; d2 <<= 1) {
        int x = (t >= d2) ? s[t - d2] : 0;
        __syncthreads();
        s[t] += x;
        __syncthreads();
    }
    if (t < NB) {
        int b = s[t] - v;
        bbase[t] = b;
        bcur[t] = b;
    }
    if (t == 0) {
        bbase[NB] = N_EDGES;
        sched_off[NFB * 32] = N_EDGES;   // global sentinel
    }
}

__global__ __launch_bounds__(PA_THREADS) void passA_kernel(
    const int* __restrict__ src, const int* __restrict__ dst,
    const int* __restrict__ etype, int* __restrict__ bcur,
    unsigned* __restrict__ tmp) {
    __shared__ int h[NB];   // block histogram
    __shared__ int gb[NB];  // global segment base for this block
    __shared__ int c[NB];   // running within-segment count
    for (int i = threadIdx.x; i < NB; i += PA_THREADS) h[i] = 0;
    __syncthreads();
    int base = blockIdx.x * PA_CHUNK;
    int d[PA_EPT];
#pragma unroll
    for (int k = 0; k < PA_EPT; ++k) {
        int e = base + k * PA_THREADS + threadIdx.x;
        d[k] = (e < N_EDGES) ? dst[e] : -1;
        if (d[k] >= 0) atomicAdd(&h[d[k] >> 8], 1);
    }
    __syncthreads();
    for (int i = threadIdx.x; i < NB; i += PA_THREADS) {
        int n = h[i];
        gb[i] = n ? atomicAdd(&bcur[i], n) : 0;
        c[i] = 0;
    }
    __syncthreads();
#pragma unroll
    for (int k = 0; k < PA_EPT; ++k) {
        int e = base + k * PA_THREADS + threadIdx.x;
        if (d[k] >= 0) {
            int b = d[k] >> 8;
            int sv = src[e], r = etype[e];
            int pos = gb[b] + atomicAdd(&c[b], 1);
            tmp[pos] = ((unsigned)(d[k] & 255) << 22) | ((unsigned)sv << 5) | (unsigned)r;
        }
    }
}

__global__ __launch_bounds__(512) void passB_kernel(
    const unsigned* __restrict__ tmp, const int* __restrict__ bbase,
    unsigned* __restrict__ edgedata, int* __restrict__ sched_off) {
    __shared__ int binpos[PB_BINS];   // 20 KB: counts -> scheduled positions
    __shared__ int blen[PB_BINS];     // 20 KB: bin lengths (saved counts)
    __shared__ unsigned sk[16 * 64];  // 4 KB: per-fb sort keys (len<<8|wloc)
    __shared__ int swo[16 * 64];      // 4 KB: per-walk scheduled offset in fb
    __shared__ int gs[512];           // 2 KB: per-fb group-total scan
    __shared__ int ssum[512];         // 2 KB: bin scan partials
    __shared__ int fbb[16];           // fb base positions
    int t = threadIdx.x;
    int b = blockIdx.x;
    int beg = bbase[b], end = bbase[b + 1];
    for (int i = t; i < PB_BINS; i += 512) binpos[i] = 0;
    __syncthreads();
    for (int i = beg + t; i < end; i += 512) {
        unsigned v = tmp[i];
        int key = (int)(v >> 22) * NUM_RELS + (int)(v & 31u);
        atomicAdd(&binpos[key], 1);
    }
    __syncthreads();
    // save lengths before scan
    for (int i = t; i < PB_BINS; i += 512) blen[i] = binpos[i];
    __syncthreads();
    // exclusive scan of 5120 bins (sorted-order bases); thread t owns 10 bins
    int loc[10];
    int sum = 0;
#pragma unroll
    for (int j = 0; j < 10; ++j) {
        loc[j] = sum;
        sum += binpos[t * 10 + j];
    }
    ssum[t] = sum;
    __syncthreads();
    for (int d2 = 1; d2 < 512; d2 <<= 1) {
        int x = (t >= d2) ? ssum[t - d2] : 0;
        __syncthreads();
        ssum[t] += x;
        __syncthreads();
    }
    int tbase = beg + ((t > 0) ? ssum[t - 1] : 0);
#pragma unroll
    for (int j = 0; j < 10; ++j) binpos[t * 10 + j] = tbase + loc[j];
    __syncthreads();
    // fb base = sorted base of its first bin
    if (t < 16) fbb[t] = binpos[t * 320];
    __syncthreads();
    // walk lengths: walk = (node_local nl, quarter qt), wloc = nl*4+qt
    for (int w = t; w < 1024; w += 512) {
        int fb = w >> 6, wloc = w & 63;
        int nl = wloc >> 2, qt = wloc & 3;
        int b0 = (fb * 16 + nl) * NUM_RELS + qt * 5;
        int len = blen[b0] + blen[b0 + 1] + blen[b0 + 2] + blen[b0 + 3] + blen[b0 + 4];
        sk[fb * 64 + wloc] = ((unsigned)len << 8) | (unsigned)wloc;
    }
    // bitonic sort desc, 64 elements per fb, 32 comparators per fb (=512 thr)
    {
        int fb = t >> 5, k = t & 31;
        unsigned* s = &sk[fb * 64];
        for (int size = 2; size <= 64; size <<= 1) {
            for (int stride = size >> 1; stride > 0; stride >>= 1) {
                __syncthreads();
                int i1 = ((k & ~(stride - 1)) << 1) | (k & (stride - 1));
                int i2 = i1 | stride;
                unsigned x = s[i1], y = s[i2];
                bool descb = (i1 & size) == 0;
                if (descb ? (x < y) : (x > y)) { s[i1] = y; s[i2] = x; }
            }
        }
    }
    __syncthreads();
    // fold-pair rank k with rank 63-k onto group slot k; scan group totals
    {
        int fb = t >> 5, k = t & 31;
        unsigned kA = sk[fb * 64 + k], kB = sk[fb * 64 + 63 - k];
        int lenA = (int)(kA >> 8), widA = (int)(kA & 63u);
        int lenB = (int)(kB >> 8), widB = (int)(kB & 63u);
        int tot = lenA + lenB;
        gs[t] = tot;
        __syncthreads();
        for (int d2 = 1; d2 < 32; d2 <<= 1) {
            int x = (k >= d2) ? gs[t - d2] : 0;
            __syncthreads();
            gs[t] += x;
            __syncthreads();
        }
        int gbase = gs[t] - tot;   // exclusive within fb
        swo[fb * 64 + widA] = gbase;
        swo[fb * 64 + widB] = gbase + lenA;
        int gfb = b * 16 + fb;
        if (gfb < NFB) sched_off[gfb * 32 + k] = fbb[fb] + gbase;
    }
    __syncthreads();
    // rewrite binpos to scheduled positions
    for (int i = t; i < PB_BINS; i += 512) {
        int node = i / 20, rel = i - node * 20;
        int fb = node >> 4, nl = node & 15;
        int qt = rel / 5, rr = rel - qt * 5;
        int wid = nl * 4 + qt;
        int base = fbb[fb] + swo[fb * 64 + wid];
        int b0 = node * 20 + qt * 5;
        for (int r = 0; r < rr; ++r) base += blen[b0 + r];
        binpos[i] = base;
    }
    __syncthreads();
    // scatter in schedule order with rowoff payload
    for (int i = beg + t; i < end; i += 512) {
        unsigned v = tmp[i];
        int dl = (int)(v >> 22), rel = (int)(v & 31u);
        int ro = rel * (16 * PADR) + (dl & 15) * PADR;
        int key = dl * NUM_RELS + rel;
        int pos = atomicAdd(&binpos[key], 1);
        edgedata[pos] = ((v >> 5) & 0x1FFFFu) | ((unsigned)ro << 17);
    }
}

// ---------------- dtype conversions ----------------

__global__ void f2b_kernel(const float* __restrict__ in, unsigned short* __restrict__ out,
                           int n4) {
    int i = blockIdx.x * 256 + threadIdx.x;
    if (i >= n4) return;
    float4 v = ((const float4*)in)[i];
    ushort4 o;
    o.x = f2bf(v.x); o.y = f2bf(v.y); o.z = f2bf(v.z); o.w = f2bf(v.w);
    ((ushort4*)out)[i] = o;
}

// W[r][d][o] fp32 -> Wb[r][o][d] bf16 (B-frag layout, verified round 4)
__global__ void wconv_kernel(const float* __restrict__ W, unsigned short* __restrict__ Wb) {
    int r = blockIdx.x;
    for (int i = threadIdx.x; i < D * D; i += 256) {
        int d2 = i >> 6, o = i & 63;
        Wb[(size_t)r * (D * D) + o * D + d2] = f2bf(W[(size_t)r * (D * D) + d2 * D + o]);
    }
}

// ---------------- fused layer ----------------
// Block = 16 dst nodes (= one fb), 8 waves. Group gidx = wave*4+grp in [0,32)
// processes the contiguous balanced span [sched_off[fb*32+gidx], +1) of
// schedule-ordered edges. Edge word carries its A-row offset ro = w>>17;
// run-reset key is ro (runs never straddle spans).
// Deep software pipeline, 4-edge batches: word buffers 3-deep (issue batch
// g+3), row buffers 2-deep (issue batch g+2), so each row-gather gets ~2
// processing phases of latency cover (spans are only ~17 edges; the old
// 8-edge/1-deep pipeline was all prologue). Slot rotation via 6-unrolled
// BOUNDED loop (lcm(3,2)) keeps all buffer indices compile-time-constant
// (no scratch) and cannot loop unboundedly. Tail merged via clamp-to-endm1
// + x=0 masking (rewrites same bf16) -> processing order identical ->
// bit-identical numerics. Waves 0-3 then do the 40-MFMA transform
// (verified layouts). mode 1: relu'd bf16; mode 2: fp32.
__global__ __launch_bounds__(512, 6) void fused_layer(
    const unsigned short* __restrict__ xb, const unsigned short* __restrict__ Wb,
    const unsigned* __restrict__ edgedata, const int* __restrict__ sched_off,
    unsigned short* __restrict__ xbout, float* __restrict__ h2out, int mode) {
    __shared__ __align__(16) unsigned short A[NUM_RELS * 16 * PADR];  // 46080 B
    int wave = threadIdx.x >> 6, lane = threadIdx.x & 63;
    int grp = lane >> 4, l4 = lane & 15;
    int gidx = wave * 4 + grp;         // 0..31
    int colb = l4 * 4;                 // column base, 0..60

    for (int i = threadIdx.x; i < NUM_RELS * 16 * PADR / 8; i += 512)
        ((int4*)A)[i] = (int4){0, 0, 0, 0};
    __syncthreads();

    int beg = sched_off[blockIdx.x * 32 + gidx];
    int end = sched_off[blockIdx.x * 32 + gidx + 1];
    int cnt = end - beg;
    int nb = (cnt + 3) >> 2;           // number of (padded) 4-edge batches
    int nbmax = max(nb, __shfl_xor(nb, 16));
    nbmax = max(nbmax, __shfl_xor(nbmax, 32));
    int endm1 = end - 1;

    float a0 = 0.f, a1 = 0.f, a2 = 0.f, a3 = 0.f;
    unsigned roprev = 0xFFFFFFFFu;
    unsigned short* Ac = A + (unsigned)colb;

    auto rowload = [&](unsigned ewv) -> uint2 {
        return *(const uint2*)(xb + ((ewv & 0x1FFFFu) << 6) + (unsigned)colb);
    };
    auto proc = [&](const unsigned (&ewc)[4], const uint2 (&xv)[4], int valid) {
#pragma unroll
        for (int j = 0; j < 4; ++j) {
            unsigned ro = ewc[j] >> 17;
            bool real = j < valid;
            unsigned mx = real ? xv[j].x : 0u;
            unsigned my = real ? xv[j].y : 0u;
            bool keep = (ro == roprev);
            a0 = (keep ? a0 : 0.f) + bf2f_lo(mx);
            a1 = (keep ? a1 : 0.f) + bf2f_hi(mx);
            a2 = (keep ? a2 : 0.f) + bf2f_lo(my);
            a3 = (keep ? a3 : 0.f) + bf2f_hi(my);
            uint2 o;
            o.x = cvt_pk_bf16(a0, a1);
            o.y = cvt_pk_bf16(a2, a3);
            *(uint2*)(Ac + ro) = o;
            roprev = ro;
        }
    };

    unsigned e0[4], e1[4], e2[4];
    uint2 v0[4], v1[4];
    // prologue: words for batches 0..2, rows for batches 0..1
    if (nb > 0) {
#pragma unroll
        for (int j = 0; j < 4; ++j) e0[j] = edgedata[min(beg + j, endm1)];
    }
    if (nb > 1) {
#pragma unroll
        for (int j = 0; j < 4; ++j) e1[j] = edgedata[min(beg + 4 + j, endm1)];
    }
    if (nb > 2) {
#pragma unroll
        for (int j = 0; j < 4; ++j) e2[j] = edgedata[min(beg + 8 + j, endm1)];
    }
    if (nb > 0) {
#pragma unroll
        for (int j = 0; j < 4; ++j) v0[j] = rowload(e0[j]);
    }
    if (nb > 1) {
#pragma unroll
        for (int j = 0; j < 4; ++j) v1[j] = rowload(e1[j]);
    }

    // PHASE(GG): copy current word/row slots; issue words(GG+3) into the
    // slot just freed; issue rows(GG+2) from word slot (GG+2)%3; process.
    // All guards are per-phase (gg vs nb/nbmax); outer loop is bounded.
#define PHASE(GG, EW0, EW2, XV0)                                              \
    {                                                                         \
        int gg = (GG);                                                        \
        if (gg < nbmax) {                                                     \
            unsigned ewc[4];                                                  \
            uint2 xvc[4];                                                     \
            _Pragma("unroll") for (int j = 0; j < 4; ++j) {                   \
                ewc[j] = EW0[j]; xvc[j] = XV0[j];                             \
            }                                                                 \
            if (gg + 3 < nb) {                                                \
                int lb = beg + (gg + 3) * 4;                                  \
                _Pragma("unroll") for (int j = 0; j < 4; ++j)                 \
                    EW0[j] = edgedata[min(lb + j, endm1)];                    \
            }                                                                 \
            if (gg + 2 < nb) {                                                \
                _Pragma("unroll") for (int j = 0; j < 4; ++j)                 \
                    XV0[j] = rowload(EW2[j]);                                 \
            }                                                                 \
            if (gg < nb) proc(ewc, xvc, cnt - gg * 4);                        \
        }                                                                     \
    }

    for (int g = 0; g < nbmax; g += 6) {
        PHASE(g + 0, e0, e2, v0)
        PHASE(g + 1, e1, e0, v1)
        PHASE(g + 2, e2, e1, v0)
        PHASE(g + 3, e0, e2, v1)
        PHASE(g + 4, e1, e0, v0)
        PHASE(g + 5, e2, e1, v1)
    }
#undef PHASE
    __syncthreads();

    // waves 0-3: transform. wave w covers output columns w*16..w*16+15
    if (wave < 4) {
        int lrow = lane & 15, lhi = lane >> 4;
        f32x4 C = {0.f, 0.f, 0.f, 0.f};
        for (int q = 0; q < NUM_RELS; ++q) {
            const unsigned short* Arow = &A[(q * 16 + lrow) * PADR + lhi * 8];
            bf16x8 aa0 = *(const bf16x8*)(Arow);        // k = lhi*8 + j
            bf16x8 aa1 = *(const bf16x8*)(Arow + 32);   // k = 32 + lhi*8 + j
            const unsigned short* wrow = Wb + ((size_t)q << 12)
                                         + (size_t)(wave * 16 + lrow) * D + lhi * 8;
            bf16x8 b0 = *(const bf16x8*)(wrow);
            bf16x8 b1 = *(const bf16x8*)(wrow + 32);
            C = __builtin_amdgcn_mfma_f32_16x16x32_bf16(aa0, b0, C, 0, 0, 0);
            C = __builtin_amdgcn_mfma_f32_16x16x32_bf16(aa1, b1, C, 0, 0, 0);
        }
        // C/D: row = lhi*4 + reg (dst-local), col = wave*16 + lrow
#pragma unroll
        for (int reg = 0; reg < 4; ++reg) {
            int onode = blockIdx.x * 16 + lhi * 4 + reg;
            int col = wave * 16 + lrow;
            if (mode == 1)
                xbout[(size_t)onode * D + col] = f2bf(fmaxf(C[reg], 0.f));
            else
                h2out[(size_t)onode * D + col] = C[reg];
        }
    }
}

// ---------------- readout ----------------

__global__ void colsum_kernel(const float* __restrict__ h2,
                              float* __restrict__ g, int n) {
    __shared__ float s[256];
    int tid = threadIdx.x;
    int col = tid & 63;
    int rowgrp = (blockIdx.x * blockDim.x + tid) >> 6;
    int nrowgrp = (gridDim.x * blockDim.x) >> 6;
    float acc = 0.0f;
    for (int row = rowgrp; row < n; row += nrowgrp)
        acc += h2[(size_t)row * D + col];
    s[tid] = acc;
    __syncthreads();
    if (tid < 64) {
        acc = s[tid] + s[tid + 64] + s[tid + 128] + s[tid + 192];
        atomicAdd(&g[col], acc);
    }
}

__global__ void mlp_kernel(const float* __restrict__ g,
                           const float* __restrict__ A1w,
                           const float* __restrict__ A1b,
                           const float* __restrict__ A2w,
                           const float* __restrict__ A2b,
                           float* __restrict__ out, float invN) {
    __shared__ float a1[HID_ATTR];
    int t = threadIdx.x;
    if (t < HID_ATTR) {
        float acc = A1b[t];
#pragma unroll
        for (int d2 = 0; d2 < D; ++d2)
            acc = fmaf(g[d2] * invN, A1w[d2 * HID_ATTR + t], acc);
        a1[t] = fmaxf(acc, 0.0f);
    }
    __syncthreads();
    if (t < OUT_ATTR) {
        float acc = A2b[t];
#pragma unroll
        for (int j = 0; j < HID_ATTR; ++j)
            acc = fmaf(a1[j], A2w[j * OUT_ATTR + t], acc);
        out[t] = 1.0f / (1.0f + expf(-acc));
    }
}

// ---------------- launch ----------------

extern "C" void kernel_launch(void* const* d_in, const int* in_sizes, int n_in,
                              void* d_out, int out_size, void* d_ws, size_t ws_size,
                              hipStream_t stream) {
    const float* h   = (const float*)d_in[0];
    const int* src   = (const int*)d_in[1];
    const int* dst   = (const int*)d_in[2];
    const int* etype = (const int*)d_in[3];
    const float* W1  = (const float*)d_in[4];
    const float* W2  = (const float*)d_in[5];
    const float* A1w = (const float*)d_in[6];
    const float* A1b = (const float*)d_in[7];
    const float* A2w = (const float*)d_in[8];
    const float* A2b = (const float*)d_in[9];

    float* out_h2 = (float*)d_out;
    float* out_a  = out_h2 + (size_t)N_NODES * D;

    // workspace layout (int offsets from d_ws; all buffers 16B-aligned)
    int* base       = (int*)d_ws;
    float* gsum     = (float*)base;               // 64 f32
    int* hist_b     = base + 64;                  // 448 (NB padded)
    int* bbase      = base + 512;                 // 448 (NB+1)
    int* bcur       = base + 960;                 // 448
    int* sched_off  = base + 1408;                // 200,064 (NFB*32 + 1 padded)
    unsigned* tmp   = (unsigned*)(base + 201472); // 3,200,000
    unsigned* edgedata = (unsigned*)(base + 3401472); // 3,200,000
    unsigned short* xb  = (unsigned short*)(base + 6601472);   // 6.4M u16
    unsigned short* xb2 = (unsigned short*)(base + 9801472);   // 6.4M u16
    unsigned short* w1b = (unsigned short*)(base + 13001472);  // 81,920 u16
    unsigned short* w2b = (unsigned short*)(base + 13042432);  // 81,920 u16
    // total: 13,083,392 ints = 52.3 MB

    hipMemsetAsync(hist_b, 0, NB * sizeof(int), stream);
    hipMemsetAsync(gsum, 0, 64 * sizeof(float), stream);

    // CSR sorted by (dst, rel) with balanced per-block schedule
    hist_bucket_kernel<<<PA_GRID, PA_THREADS, 0, stream>>>(dst, hist_b);
    scan_bucket_kernel<<<1, 512, 0, stream>>>(hist_b, bbase, bcur, sched_off);
    passA_kernel<<<PA_GRID, PA_THREADS, 0, stream>>>(src, dst, etype, bcur, tmp);
    passB_kernel<<<NB, 512, 0, stream>>>(tmp, bbase, edgedata, sched_off);

    // conversions
    wconv_kernel<<<NUM_RELS, 256, 0, stream>>>(W1, w1b);
    wconv_kernel<<<NUM_RELS, 256, 0, stream>>>(W2, w2b);
    f2b_kernel<<<(N_NODES * D / 4 + 255) / 256, 256, 0, stream>>>(h, xb, N_NODES * D / 4);

    // two fused RGCN layers
    fused_layer<<<NFB, 512, 0, stream>>>(xb, w1b, edgedata, sched_off,
                                         xb2, nullptr, 1);
    fused_layer<<<NFB, 512, 0, stream>>>(xb2, w2b, edgedata, sched_off,
                                         nullptr, out_h2, 2);

    // readout
    colsum_kernel<<<512, 256, 0, stream>>>(out_h2, gsum, N_NODES);
    mlp_kernel<<<1, 64, 0, stream>>>(gsum, A1w, A1b, A2w, A2b,
                                     out_a, 1.0f / (float)N_NODES);
}

// Round 8
// 571.302 us; speedup vs baseline: 1.0104x; 1.0104x over previous
//
#include <hip/hip_runtime.h>
#include <hip/hip_bf16.h>
#include <math.h>
#include <stdint.h>

#define N_NODES 100000
#define N_EDGES 3200000
#define D 64
#define NUM_RELS 20
#define HID_ATTR 32
#define OUT_ATTR 10
#define PADR 72                          // A-tile row stride in bf16 (144 B)
#define NFB (N_NODES / 16)               // 6250 fused blocks (16 nodes each)

// two-level MSD counting sort
#define BUCKET_DSTS 256                  // dsts per coarse bucket (dst >> 8)
#define NB 391                           // ceil(100000 / 256)
#define PA_THREADS 512
#define PA_EPT 16                        // edges per thread
#define PA_CHUNK (PA_THREADS * PA_EPT)   // 8192
#define PA_GRID 391                      // ceil(3.2M / 8192)
#define PB_BINS (BUCKET_DSTS * NUM_RELS) // 5120 fine bins per bucket

typedef __attribute__((ext_vector_type(8))) short bf16x8;
typedef __attribute__((ext_vector_type(4))) float f32x4;

static __device__ __forceinline__ unsigned short f2bf(float x) {
    unsigned u = __builtin_bit_cast(unsigned, x);
    unsigned r = (u + 0x7FFFu + ((u >> 16) & 1u)) >> 16;
    return (unsigned short)r;
}
static __device__ __forceinline__ float bf2f(unsigned short b) {
    return __builtin_bit_cast(float, (unsigned)b << 16);
}
static __device__ __forceinline__ float bf2f_lo(unsigned u) {
    return __builtin_bit_cast(float, u << 16);
}
static __device__ __forceinline__ float bf2f_hi(unsigned u) {
    return __builtin_bit_cast(float, u & 0xFFFF0000u);
}
// packed f32->bf16 RNE (bit-identical to f2bf above for finite inputs)
static __device__ __forceinline__ unsigned cvt_pk_bf16(float lo, float hi) {
    unsigned r;
    asm("v_cvt_pk_bf16_f32 %0, %1, %2" : "=v"(r) : "v"(lo), "v"(hi));
    return r;
}

// ---------------- CSR build: 2-level MSD counting sort + balanced schedule --
// level 1 key: dst >> 8 (391 buckets); level 2 key: (dst&255)*20 + rel.
// tmp payload u32: dstLow[29:22] | src[21:5] | rel[4:0]
// passB: per 16-node fused-block, split each node into 4 rel-quarter walks
// (64 walks), bitonic-sort lengths desc, fold-pair rank k with rank 63-k onto
// 32 group slots, lay edges out in schedule order, emit sched_off[fb*32+g].
// Final edgedata payload: src[16:0] | rowoff[31:17],
//   rowoff = rel*(16*PADR) + (dstLow&15)*PADR  (<= 22968 < 2^15).
// Runs (same (dst,rel)) stay contiguous & whole.

__global__ void hist_bucket_kernel(const int* __restrict__ dst, int* __restrict__ hist) {
    __shared__ int h[NB];
    for (int i = threadIdx.x; i < NB; i += PA_THREADS) h[i] = 0;
    __syncthreads();
    int base = blockIdx.x * PA_CHUNK;
#pragma unroll
    for (int k = 0; k < PA_EPT; ++k) {
        int e = base + k * PA_THREADS + threadIdx.x;
        if (e < N_EDGES) atomicAdd(&h[dst[e] >> 8], 1);
    }
    __syncthreads();
    for (int i = threadIdx.x; i < NB; i += PA_THREADS)
        if (h[i]) atomicAdd(&hist[i], h[i]);
}

__global__ void scan_bucket_kernel(const int* __restrict__ hist, int* __restrict__ bbase,
                                   int* __restrict__ bcur, int* __restrict__ sched_off) {
    __shared__ int s[512];
    int t = threadIdx.x;
    int v = (t < NB) ? hist[t] : 0;
    s[t] = v;
    __syncthreads();
    for (int d2 = 1; d2 < 512; d2 <<= 1) {
        int x = (t >= d2) ? s[t - d2] : 0;
        __syncthreads();
        s[t] += x;
        __syncthreads();
    }
    if (t < NB) {
        int b = s[t] - v;
        bbase[t] = b;
        bcur[t] = b;
    }
    if (t == 0) {
        bbase[NB] = N_EDGES;
        sched_off[NFB * 32] = N_EDGES;   // global sentinel
    }
}

__global__ __launch_bounds__(PA_THREADS) void passA_kernel(
    const int* __restrict__ src, const int* __restrict__ dst,
    const int* __restrict__ etype, int* __restrict__ bcur,
    unsigned* __restrict__ tmp) {
    __shared__ int h[NB];   // block histogram
    __shared__ int gb[NB];  // global segment base for this block
    __shared__ int c[NB];   // running within-segment count
    for (int i = threadIdx.x; i < NB; i += PA_THREADS) h[i] = 0;
    __syncthreads();
    int base = blockIdx.x * PA_CHUNK;
    int d[PA_EPT];
#pragma unroll
    for (int k = 0; k < PA_EPT; ++k) {
        int e = base + k * PA_THREADS + threadIdx.x;
        d[k] = (e < N_EDGES) ? dst[e] : -1;
        if (d[k] >= 0) atomicAdd(&h[d[k] >> 8], 1);
    }
    __syncthreads();
    for (int i = threadIdx.x; i < NB; i += PA_THREADS) {
        int n = h[i];
        gb[i] = n ? atomicAdd(&bcur[i], n) : 0;
        c[i] = 0;
    }
    __syncthreads();
#pragma unroll
    for (int k = 0; k < PA_EPT; ++k) {
        int e = base + k * PA_THREADS + threadIdx.x;
        if (d[k] >= 0) {
            int b = d[k] >> 8;
            int sv = src[e], r = etype[e];
            int pos = gb[b] + atomicAdd(&c[b], 1);
            tmp[pos] = ((unsigned)(d[k] & 255) << 22) | ((unsigned)sv << 5) | (unsigned)r;
        }
    }
}

__global__ __launch_bounds__(512) void passB_kernel(
    const unsigned* __restrict__ tmp, const int* __restrict__ bbase,
    unsigned* __restrict__ edgedata, int* __restrict__ sched_off) {
    __shared__ int binpos[PB_BINS];   // 20 KB: counts -> scheduled positions
    __shared__ int blen[PB_BINS];     // 20 KB: bin lengths (saved counts)
    __shared__ unsigned sk[16 * 64];  // 4 KB: per-fb sort keys (len<<8|wloc)
    __shared__ int swo[16 * 64];      // 4 KB: per-walk scheduled offset in fb
    __shared__ int gs[512];           // 2 KB: per-fb group-total scan
    __shared__ int ssum[512];         // 2 KB: bin scan partials
    __shared__ int fbb[16];           // fb base positions
    int t = threadIdx.x;
    int b = blockIdx.x;
    int beg = bbase[b], end = bbase[b + 1];
    for (int i = t; i < PB_BINS; i += 512) binpos[i] = 0;
    __syncthreads();
    for (int i = beg + t; i < end; i += 512) {
        unsigned v = tmp[i];
        int key = (int)(v >> 22) * NUM_RELS + (int)(v & 31u);
        atomicAdd(&binpos[key], 1);
    }
    __syncthreads();
    // save lengths before scan
    for (int i = t; i < PB_BINS; i += 512) blen[i] = binpos[i];
    __syncthreads();
    // exclusive scan of 5120 bins (sorted-order bases); thread t owns 10 bins
    int loc[10];
    int sum = 0;
#pragma unroll
    for (int j = 0; j < 10; ++j) {
        loc[j] = sum;
        sum += binpos[t * 10 + j];
    }
    ssum[t] = sum;
    __syncthreads();
    for (int d2 = 1; d2 < 512; d2 <<= 1) {
        int x = (t >= d2) ? ssum[t - d2] : 0;
        __syncthreads();
        ssum[t] += x;
        __syncthreads();
    }
    int tbase = beg + ((t > 0) ? ssum[t - 1] : 0);
#pragma unroll
    for (int j = 0; j < 10; ++j) binpos[t * 10 + j] = tbase + loc[j];
    __syncthreads();
    // fb base = sorted base of its first bin
    if (t < 16) fbb[t] = binpos[t * 320];
    __syncthreads();
    // walk lengths: walk = (node_local nl, quarter qt), wloc = nl*4+qt
    for (int w = t; w < 1024; w += 512) {
        int fb = w >> 6, wloc = w & 63;
        int nl = wloc >> 2, qt = wloc & 3;
        int b0 = (fb * 16 + nl) * NUM_RELS + qt * 5;
        int len = blen[b0] + blen[b0 + 1] + blen[b0 + 2] + blen[b0 + 3] + blen[b0 + 4];
        sk[fb * 64 + wloc] = ((unsigned)len << 8) | (unsigned)wloc;
    }
    // bitonic sort desc, 64 elements per fb, 32 comparators per fb (=512 thr)
    {
        int fb = t >> 5, k = t & 31;
        unsigned* s = &sk[fb * 64];
        for (int size = 2; size <= 64; size <<= 1) {
            for (int stride = size >> 1; stride > 0; stride >>= 1) {
                __syncthreads();
                int i1 = ((k & ~(stride - 1)) << 1) | (k & (stride - 1));
                int i2 = i1 | stride;
                unsigned x = s[i1], y = s[i2];
                bool descb = (i1 & size) == 0;
                if (descb ? (x < y) : (x > y)) { s[i1] = y; s[i2] = x; }
            }
        }
    }
    __syncthreads();
    // fold-pair rank k with rank 63-k onto group slot k; scan group totals
    {
        int fb = t >> 5, k = t & 31;
        unsigned kA = sk[fb * 64 + k], kB = sk[fb * 64 + 63 - k];
        int lenA = (int)(kA >> 8), widA = (int)(kA & 63u);
        int lenB = (int)(kB >> 8), widB = (int)(kB & 63u);
        int tot = lenA + lenB;
        gs[t] = tot;
        __syncthreads();
        for (int d2 = 1; d2 < 32; d2 <<= 1) {
            int x = (k >= d2) ? gs[t - d2] : 0;
            __syncthreads();
            gs[t] += x;
            __syncthreads();
        }
        int gbase = gs[t] - tot;   // exclusive within fb
        swo[fb * 64 + widA] = gbase;
        swo[fb * 64 + widB] = gbase + lenA;
        int gfb = b * 16 + fb;
        if (gfb < NFB) sched_off[gfb * 32 + k] = fbb[fb] + gbase;
    }
    __syncthreads();
    // rewrite binpos to scheduled positions
    for (int i = t; i < PB_BINS; i += 512) {
        int node = i / 20, rel = i - node * 20;
        int fb = node >> 4, nl = node & 15;
        int qt = rel / 5, rr = rel - qt * 5;
        int wid = nl * 4 + qt;
        int base = fbb[fb] + swo[fb * 64 + wid];
        int b0 = node * 20 + qt * 5;
        for (int r = 0; r < rr; ++r) base += blen[b0 + r];
        binpos[i] = base;
    }
    __syncthreads();
    // scatter in schedule order with rowoff payload
    for (int i = beg + t; i < end; i += 512) {
        unsigned v = tmp[i];
        int dl = (int)(v >> 22), rel = (int)(v & 31u);
        int ro = rel * (16 * PADR) + (dl & 15) * PADR;
        int key = dl * NUM_RELS + rel;
        int pos = atomicAdd(&binpos[key], 1);
        edgedata[pos] = ((v >> 5) & 0x1FFFFu) | ((unsigned)ro << 17);
    }
}

// ---------------- dtype conversions ----------------

__global__ void f2b_kernel(const float* __restrict__ in, unsigned short* __restrict__ out,
                           int n4) {
    int i = blockIdx.x * 256 + threadIdx.x;
    if (i >= n4) return;
    float4 v = ((const float4*)in)[i];
    ushort4 o;
    o.x = f2bf(v.x); o.y = f2bf(v.y); o.z = f2bf(v.z); o.w = f2bf(v.w);
    ((ushort4*)out)[i] = o;
}

// W[r][d][o] fp32 -> Wb[r][o][d] bf16 (B-frag layout, verified round 4)
__global__ void wconv_kernel(const float* __restrict__ W, unsigned short* __restrict__ Wb) {
    int r = blockIdx.x;
    for (int i = threadIdx.x; i < D * D; i += 256) {
        int d2 = i >> 6, o = i & 63;
        Wb[(size_t)r * (D * D) + o * D + d2] = f2bf(W[(size_t)r * (D * D) + d2 * D + o]);
    }
}

// ---------------- fused layer ----------------
// Block = 16 dst nodes (= one fb), 8 waves. Group gidx = wave*4+grp in [0,32)
// processes the contiguous balanced span [sched_off[fb*32+gidx], +1) of
// schedule-ordered edges. Edge word carries its A-row offset ro = w>>17;
// run-reset key is ro (runs never straddle spans).
// Deep software pipeline, 4-edge batches: word buffers 3-deep (issue batch
// g+3), row buffers 2-deep (issue batch g+2). THE PIN: R7 showed hipcc sinks
// the prefetch loads to their uses (VGPR stayed 40), re-serializing the
// pipeline -> __builtin_amdgcn_sched_barrier(0) between the load-issue
// section and proc in every phase forbids that motion. Prologue VMEM is
// issued BEFORE __syncthreads so the barrier's vmcnt drain completes it
// while waves wait anyway. Tail merged via clamp-to-endm1 + x=0 masking
// (rewrites same bf16) -> per-lane op order identical -> bit-identical
// numerics. Waves 0-3 then do the 40-MFMA transform (verified layouts).
// mode 1: relu'd bf16; mode 2: fp32.
__global__ __launch_bounds__(512, 6) void fused_layer(
    const unsigned short* __restrict__ xb, const unsigned short* __restrict__ Wb,
    const unsigned* __restrict__ edgedata, const int* __restrict__ sched_off,
    unsigned short* __restrict__ xbout, float* __restrict__ h2out, int mode) {
    __shared__ __align__(16) unsigned short A[NUM_RELS * 16 * PADR];  // 46080 B
    int wave = threadIdx.x >> 6, lane = threadIdx.x & 63;
    int grp = lane >> 4, l4 = lane & 15;
    int gidx = wave * 4 + grp;         // 0..31
    int colb = l4 * 4;                 // column base, 0..60

    // issue span-bound loads first (longest dependence chain)
    int beg = sched_off[blockIdx.x * 32 + gidx];
    int end = sched_off[blockIdx.x * 32 + gidx + 1];

    // A-init overlaps the sched_off latency (independent stores)
    for (int i = threadIdx.x; i < NUM_RELS * 16 * PADR / 8; i += 512)
        ((int4*)A)[i] = (int4){0, 0, 0, 0};

    int cnt = end - beg;
    int nb = (cnt + 3) >> 2;           // number of (padded) 4-edge batches
    int nbmax = max(nb, __shfl_xor(nb, 16));
    nbmax = max(nbmax, __shfl_xor(nbmax, 32));
    int endm1 = end - 1;

    float a0 = 0.f, a1 = 0.f, a2 = 0.f, a3 = 0.f;
    unsigned roprev = 0xFFFFFFFFu;
    unsigned short* Ac = A + (unsigned)colb;

    auto rowload = [&](unsigned ewv) -> uint2 {
        return *(const uint2*)(xb + ((ewv & 0x1FFFFu) << 6) + (unsigned)colb);
    };
    auto proc = [&](const unsigned (&ewc)[4], const uint2 (&xv)[4], int valid) {
#pragma unroll
        for (int j = 0; j < 4; ++j) {
            unsigned ro = ewc[j] >> 17;
            bool real = j < valid;
            unsigned mx = real ? xv[j].x : 0u;
            unsigned my = real ? xv[j].y : 0u;
            bool keep = (ro == roprev);
            a0 = (keep ? a0 : 0.f) + bf2f_lo(mx);
            a1 = (keep ? a1 : 0.f) + bf2f_hi(mx);
            a2 = (keep ? a2 : 0.f) + bf2f_lo(my);
            a3 = (keep ? a3 : 0.f) + bf2f_hi(my);
            uint2 o;
            o.x = cvt_pk_bf16(a0, a1);
            o.y = cvt_pk_bf16(a2, a3);
            *(uint2*)(Ac + ro) = o;
            roprev = ro;
        }
    };

    unsigned e0[4], e1[4], e2[4];
    uint2 v0[4], v1[4];
    // prologue (pure VMEM, before the barrier): words for batches 0..2,
    // rows for batches 0..1
    if (nb > 0) {
#pragma unroll
        for (int j = 0; j < 4; ++j) e0[j] = edgedata[min(beg + j, endm1)];
    }
    if (nb > 1) {
#pragma unroll
        for (int j = 0; j < 4; ++j) e1[j] = edgedata[min(beg + 4 + j, endm1)];
    }
    if (nb > 2) {
#pragma unroll
        for (int j = 0; j < 4; ++j) e2[j] = edgedata[min(beg + 8 + j, endm1)];
    }
    if (nb > 0) {
#pragma unroll
        for (int j = 0; j < 4; ++j) v0[j] = rowload(e0[j]);
    }
    if (nb > 1) {
#pragma unroll
        for (int j = 0; j < 4; ++j) v1[j] = rowload(e1[j]);
    }
    __builtin_amdgcn_sched_barrier(0);
    __syncthreads();   // A-init visible; prologue loads drain during the wait

    // PHASE(GG): copy current word/row slots; issue words(GG+3) into the
    // slot just freed; issue rows(GG+2) from word slot (GG+2)%3;
    // sched_barrier pins the issues ABOVE proc; then process.
#define PHASE(GG, EW0, EW2, XV0)                                              \
    {                                                                         \
        int gg = (GG);                                                        \
        if (gg < nbmax) {                                                     \
            unsigned ewc[4];                                                  \
            uint2 xvc[4];                                                     \
            _Pragma("unroll") for (int j = 0; j < 4; ++j) {                   \
                ewc[j] = EW0[j]; xvc[j] = XV0[j];                             \
            }                                                                 \
            if (gg + 3 < nb) {                                                \
                int lb = beg + (gg + 3) * 4;                                  \
                _Pragma("unroll") for (int j = 0; j < 4; ++j)                 \
                    EW0[j] = edgedata[min(lb + j, endm1)];                    \
            }                                                                 \
            if (gg + 2 < nb) {                                                \
                _Pragma("unroll") for (int j = 0; j < 4; ++j)                 \
                    XV0[j] = rowload(EW2[j]);                                 \
            }                                                                 \
            __builtin_amdgcn_sched_barrier(0);                                \
            if (gg < nb) proc(ewc, xvc, cnt - gg * 4);                        \
        }                                                                     \
    }

    for (int g = 0; g < nbmax; g += 6) {
        PHASE(g + 0, e0, e2, v0)
        PHASE(g + 1, e1, e0, v1)
        PHASE(g + 2, e2, e1, v0)
        PHASE(g + 3, e0, e2, v1)
        PHASE(g + 4, e1, e0, v0)
        PHASE(g + 5, e2, e1, v1)
    }
#undef PHASE
    __syncthreads();

    // waves 0-3: transform. wave w covers output columns w*16..w*16+15
    if (wave < 4) {
        int lrow = lane & 15, lhi = lane >> 4;
        f32x4 C = {0.f, 0.f, 0.f, 0.f};
        for (int q = 0; q < NUM_RELS; ++q) {
            const unsigned short* Arow = &A[(q * 16 + lrow) * PADR + lhi * 8];
            bf16x8 aa0 = *(const bf16x8*)(Arow);        // k = lhi*8 + j
            bf16x8 aa1 = *(const bf16x8*)(Arow + 32);   // k = 32 + lhi*8 + j
            const unsigned short* wrow = Wb + ((size_t)q << 12)
                                         + (size_t)(wave * 16 + lrow) * D + lhi * 8;
            bf16x8 b0 = *(const bf16x8*)(wrow);
            bf16x8 b1 = *(const bf16x8*)(wrow + 32);
            C = __builtin_amdgcn_mfma_f32_16x16x32_bf16(aa0, b0, C, 0, 0, 0);
            C = __builtin_amdgcn_mfma_f32_16x16x32_bf16(aa1, b1, C, 0, 0, 0);
        }
        // C/D: row = lhi*4 + reg (dst-local), col = wave*16 + lrow
#pragma unroll
        for (int reg = 0; reg < 4; ++reg) {
            int onode = blockIdx.x * 16 + lhi * 4 + reg;
            int col = wave * 16 + lrow;
            if (mode == 1)
                xbout[(size_t)onode * D + col] = f2bf(fmaxf(C[reg], 0.f));
            else
                h2out[(size_t)onode * D + col] = C[reg];
        }
    }
}

// ---------------- readout ----------------

__global__ void colsum_kernel(const float* __restrict__ h2,
                              float* __restrict__ g, int n) {
    __shared__ float s[256];
    int tid = threadIdx.x;
    int col = tid & 63;
    int rowgrp = (blockIdx.x * blockDim.x + tid) >> 6;
    int nrowgrp = (gridDim.x * blockDim.x) >> 6;
    float acc = 0.0f;
    for (int row = rowgrp; row < n; row += nrowgrp)
        acc += h2[(size_t)row * D + col];
    s[tid] = acc;
    __syncthreads();
    if (tid < 64) {
        acc = s[tid] + s[tid + 64] + s[tid + 128] + s[tid + 192];
        atomicAdd(&g[col], acc);
    }
}

__global__ void mlp_kernel(const float* __restrict__ g,
                           const float* __restrict__ A1w,
                           const float* __restrict__ A1b,
                           const float* __restrict__ A2w,
                           const float* __restrict__ A2b,
                           float* __restrict__ out, float invN) {
    __shared__ float a1[HID_ATTR];
    int t = threadIdx.x;
    if (t < HID_ATTR) {
        float acc = A1b[t];
#pragma unroll
        for (int d2 = 0; d2 < D; ++d2)
            acc = fmaf(g[d2] * invN, A1w[d2 * HID_ATTR + t], acc);
        a1[t] = fmaxf(acc, 0.0f);
    }
    __syncthreads();
    if (t < OUT_ATTR) {
        float acc = A2b[t];
#pragma unroll
        for (int j = 0; j < HID_ATTR; ++j)
            acc = fmaf(a1[j], A2w[j * OUT_ATTR + t], acc);
        out[t] = 1.0f / (1.0f + expf(-acc));
    }
}

// ---------------- launch ----------------

extern "C" void kernel_launch(void* const* d_in, const int* in_sizes, int n_in,
                              void* d_out, int out_size, void* d_ws, size_t ws_size,
                              hipStream_t stream) {
    const float* h   = (const float*)d_in[0];
    const int* src   = (const int*)d_in[1];
    const int* dst   = (const int*)d_in[2];
    const int* etype = (const int*)d_in[3];
    const float* W1  = (const float*)d_in[4];
    const float* W2  = (const float*)d_in[5];
    const float* A1w = (const float*)d_in[6];
    const float* A1b = (const float*)d_in[7];
    const float* A2w = (const float*)d_in[8];
    const float* A2b = (const float*)d_in[9];

    float* out_h2 = (float*)d_out;
    float* out_a  = out_h2 + (size_t)N_NODES * D;

    // workspace layout (int offsets from d_ws; all buffers 16B-aligned)
    int* base       = (int*)d_ws;
    float* gsum     = (float*)base;               // 64 f32
    int* hist_b     = base + 64;                  // 448 (NB padded)
    int* bbase      = base + 512;                 // 448 (NB+1)
    int* bcur       = base + 960;                 // 448
    int* sched_off  = base + 1408;                // 200,064 (NFB*32 + 1 padded)
    unsigned* tmp   = (unsigned*)(base + 201472); // 3,200,000
    unsigned* edgedata = (unsigned*)(base + 3401472); // 3,200,000
    unsigned short* xb  = (unsigned short*)(base + 6601472);   // 6.4M u16
    unsigned short* xb2 = (unsigned short*)(base + 9801472);   // 6.4M u16
    unsigned short* w1b = (unsigned short*)(base + 13001472);  // 81,920 u16
    unsigned short* w2b = (unsigned short*)(base + 13042432);  // 81,920 u16
    // total: 13,083,392 ints = 52.3 MB

    hipMemsetAsync(hist_b, 0, NB * sizeof(int), stream);
    hipMemsetAsync(gsum, 0, 64 * sizeof(float), stream);

    // CSR sorted by (dst, rel) with balanced per-block schedule
    hist_bucket_kernel<<<PA_GRID, PA_THREADS, 0, stream>>>(dst, hist_b);
    scan_bucket_kernel<<<1, 512, 0, stream>>>(hist_b, bbase, bcur, sched_off);
    passA_kernel<<<PA_GRID, PA_THREADS, 0, stream>>>(src, dst, etype, bcur, tmp);
    passB_kernel<<<NB, 512, 0, stream>>>(tmp, bbase, edgedata, sched_off);

    // conversions
    wconv_kernel<<<NUM_RELS, 256, 0, stream>>>(W1, w1b);
    wconv_kernel<<<NUM_RELS, 256, 0, stream>>>(W2, w2b);
    f2b_kernel<<<(N_NODES * D / 4 + 255) / 256, 256, 0, stream>>>(h, xb, N_NODES * D / 4);

    // two fused RGCN layers
    fused_layer<<<NFB, 512, 0, stream>>>(xb, w1b, edgedata, sched_off,
                                         xb2, nullptr, 1);
    fused_layer<<<NFB, 512, 0, stream>>>(xb2, w2b, edgedata, sched_off,
                                         nullptr, out_h2, 2);

    // readout
    colsum_kernel<<<512, 256, 0, stream>>>(out_h2, gsum, N_NODES);
    mlp_kernel<<<1, 64, 0, stream>>>(gsum, A1w, A1b, A2w, A2b,
                                     out_a, 1.0f / (float)N_NODES);
}